// Round 1
// baseline (394.024 us; speedup 1.0000x reference)
//
#include <hip/hip_runtime.h>
#include <hip/hip_bf16.h>
#include <math.h>

#define EPS 1e-8f

// ---------- helpers ----------
__device__ __forceinline__ unsigned fenc(float f) {
    unsigned u = __float_as_uint(f);
    return (u & 0x80000000u) ? ~u : (u | 0x80000000u);
}
__device__ __forceinline__ float fdec(unsigned e) {
    unsigned u = (e & 0x80000000u) ? (e & 0x7FFFFFFFu) : ~e;
    return __uint_as_float(u);
}

__device__ __forceinline__ float block_sum(float v, float* red) {
    red[threadIdx.x] = v;
    __syncthreads();
    for (int k = 128; k > 0; k >>= 1) {
        if (threadIdx.x < k) red[threadIdx.x] += red[threadIdx.x + k];
        __syncthreads();
    }
    float r = red[0];
    __syncthreads();
    return r;
}
__device__ __forceinline__ float block_max(float v, float* red) {
    red[threadIdx.x] = v;
    __syncthreads();
    for (int k = 128; k > 0; k >>= 1) {
        if (threadIdx.x < k) red[threadIdx.x] = fmaxf(red[threadIdx.x], red[threadIdx.x + k]);
        __syncthreads();
    }
    float r = red[0];
    __syncthreads();
    return r;
}

// ---------- kernels ----------
__global__ void k_init(int* counts, int* cursors, unsigned* minmax, int C) {
    int i = blockIdx.x * blockDim.x + threadIdx.x;
    if (i < C) { counts[i] = 0; cursors[i] = 0; }
    if (i == 0) { minmax[0] = 0xFFFFFFFFu; minmax[1] = 0u; }
}

__global__ void k_hist(const int* tgt, int* counts, int B) {
    int i = blockIdx.x * blockDim.x + threadIdx.x;
    if (i < B) atomicAdd(&counts[tgt[i]], 1);
}

__global__ void k_prefix(const int* counts, int* offsets, int C) {
    __shared__ int buf[1024];
    int t = threadIdx.x;
    int v0 = (t < C) ? counts[t] : 0;
    buf[t] = v0;
    __syncthreads();
    for (int off = 1; off < 1024; off <<= 1) {
        int v = (t >= off) ? buf[t - off] : 0;
        __syncthreads();
        buf[t] += v;
        __syncthreads();
    }
    if (t < C) offsets[t] = buf[t] - v0;
}

__global__ void k_scatter(const int* tgt, const int* offsets, int* cursors, int* idx, int B) {
    int i = blockIdx.x * blockDim.x + threadIdx.x;
    if (i < B) {
        int t = tgt[i];
        int p = atomicAdd(&cursors[t], 1);
        idx[offsets[t] + p] = i;
    }
}

__global__ void k_sortlists(const int* counts, const int* offsets, int* idx, int C) {
    int c = blockIdx.x * blockDim.x + threadIdx.x;
    if (c >= C) return;
    int o = offsets[c], n = counts[c];
    for (int i = 1; i < n; i++) {
        int v = idx[o + i];
        int j = i - 1;
        while (j >= 0 && idx[o + j] > v) { idx[o + j + 1] = idx[o + j]; j--; }
        idx[o + j + 1] = v;
    }
}

// one block (256 thr) per class; D = 1024
__global__ void k_ftab(const float* feat, const float* finit, const int* counts,
                       const int* offsets, const int* idx, float* ftab, int C, int D) {
    int c = blockIdx.x, t = threadIdx.x;
    int n = counts[c];
    if (n == 0) {
        for (int d = t; d < D; d += 256) ftab[(long)c * D + d] = finit[(long)c * D + d];
        return;
    }
    float acc[4] = {0.f, 0.f, 0.f, 0.f};
    int o = offsets[c];
    for (int i = 0; i < n; i++) {
        const float* row = feat + (long)idx[o + i] * D;
#pragma unroll
        for (int j = 0; j < 4; j++) acc[j] += row[t + j * 256];
    }
    float inv = 1.0f / (float)n;
#pragma unroll
    for (int j = 0; j < 4; j++) ftab[(long)c * D + t + j * 256] = acc[j] * inv;
}

// one block per class; C2 = 1000 columns
__global__ void k_ltab(const float* logits, const float* linit, const int* counts,
                       const int* offsets, const int* idx, float* ltab, int C, int C2) {
    int c = blockIdx.x, t = threadIdx.x;
    int n = counts[c];
    if (n == 0) {
        for (int d = t; d < C2; d += 256) ltab[(long)c * C2 + d] = linit[(long)c * C2 + d];
        return;
    }
    float acc[4] = {0.f, 0.f, 0.f, 0.f};
    int o = offsets[c];
    for (int i = 0; i < n; i++) {
        const float* row = logits + (long)idx[o + i] * C2;
#pragma unroll
        for (int j = 0; j < 4; j++) {
            int d = t + j * 256;
            if (d < C2) acc[j] += row[d];
        }
    }
    float inv = 1.0f / (float)n;
#pragma unroll
    for (int j = 0; j < 4; j++) {
        int d = t + j * 256;
        if (d < C2) ltab[(long)c * C2 + d] = acc[j] * inv;
    }
}

__global__ void k_norms(const float* ftab, float* norms, int C, int D) {
    __shared__ float red[256];
    int c = blockIdx.x;
    float s = 0.f;
    for (int d = threadIdx.x; d < D; d += 256) {
        float v = ftab[(long)c * D + d];
        s += v * v;
    }
    s = block_sum(s, red);
    if (threadIdx.x == 0) norms[c] = sqrtf(s);
}

// S = (A A^T) / outer(norms); 64x64 tile per block, 4x4 per thread
__global__ __launch_bounds__(256) void k_gemm(const float* A, const float* norms, float* S,
                                              unsigned* minmax, int C, int D) {
    __shared__ float As[64][17];
    __shared__ float Bs[64][17];
    int tx = threadIdx.x % 16, ty = threadIdx.x / 16;
    int rb = blockIdx.y * 64, cb = blockIdx.x * 64;
    float acc[4][4] = {};
    for (int k0 = 0; k0 < D; k0 += 16) {
        for (int i = threadIdx.x; i < 64 * 16; i += 256) {
            int r = i / 16, k = i % 16;
            As[r][k] = (rb + r < C) ? A[(long)(rb + r) * D + k0 + k] : 0.f;
            Bs[r][k] = (cb + r < C) ? A[(long)(cb + r) * D + k0 + k] : 0.f;
        }
        __syncthreads();
#pragma unroll
        for (int k = 0; k < 16; k++) {
            float a[4], b[4];
#pragma unroll
            for (int i = 0; i < 4; i++) a[i] = As[ty * 4 + i][k];
#pragma unroll
            for (int j = 0; j < 4; j++) b[j] = Bs[tx * 4 + j][k];
#pragma unroll
            for (int i = 0; i < 4; i++)
#pragma unroll
                for (int j = 0; j < 4; j++) acc[i][j] += a[i] * b[j];
        }
        __syncthreads();
    }
    float lmin = INFINITY, lmax = -INFINITY;
#pragma unroll
    for (int i = 0; i < 4; i++)
#pragma unroll
        for (int j = 0; j < 4; j++) {
            int r = rb + ty * 4 + i, cc = cb + tx * 4 + j;
            if (r < C && cc < C) {
                float v = acc[i][j] / (norms[r] * norms[cc]);
                S[(long)r * C + cc] = v;
                lmin = fminf(lmin, v);
                lmax = fmaxf(lmax, v);
            }
        }
    __shared__ float rmin[256], rmax[256];
    rmin[threadIdx.x] = lmin;
    rmax[threadIdx.x] = lmax;
    __syncthreads();
    for (int k = 128; k > 0; k >>= 1) {
        if (threadIdx.x < k) {
            rmin[threadIdx.x] = fminf(rmin[threadIdx.x], rmin[threadIdx.x + k]);
            rmax[threadIdx.x] = fmaxf(rmax[threadIdx.x], rmax[threadIdx.x + k]);
        }
        __syncthreads();
    }
    if (threadIdx.x == 0) {
        atomicMin(&minmax[0], fenc(rmin[0]));
        atomicMax(&minmax[1], fenc(rmax[0]));
    }
}

// per-row max/argmax excluding diagonal; normalize with cmin/cmax
__global__ void k_rowmax(const float* S, const unsigned* minmax, float* simval, int* simcls, int C) {
    __shared__ float rv[256];
    __shared__ int ri[256];
    int c = blockIdx.x, t = threadIdx.x;
    float best = -INFINITY;
    int bi = 0x7FFFFFFF;
    for (int j = t; j < C; j += 256) {
        if (j == c) continue;
        float v = S[(long)c * C + j];
        if (v > best) { best = v; bi = j; }
    }
    rv[t] = best;
    ri[t] = bi;
    __syncthreads();
    for (int k = 128; k > 0; k >>= 1) {
        if (t < k) {
            if (rv[t + k] > rv[t] || (rv[t + k] == rv[t] && ri[t + k] < ri[t])) {
                rv[t] = rv[t + k];
                ri[t] = ri[t + k];
            }
        }
        __syncthreads();
    }
    if (t == 0) {
        float cmin = fdec(minmax[0]);
        float cmax = fdec(minmax[1]);
        simval[c] = (rv[0] - cmin) / (cmax - cmin);
        simcls[c] = ri[0];
    }
}

// one wave per sample; 4 samples per block
__global__ void k_floss(const float* feat, const float* ftab, const float* norms, const int* tgt,
                        const float* simval, const int* simcls, float* fpart, int B, int D) {
    int wid = threadIdx.x >> 6, lane = threadIdx.x & 63;
    int s = blockIdx.x * 4 + wid;
    int cls = tgt[s];
    int sc = simcls[cls];
    const float* f = feat + (long)s * D;
    const float* ft = ftab + (long)cls * D;
    const float* fs = ftab + (long)sc * D;
    float d1 = 0.f, d2 = 0.f, nf2 = 0.f;
    for (int j = lane; j < D; j += 64) {
        float x = f[j];
        d1 += x * ft[j];
        d2 += x * fs[j];
        nf2 += x * x;
    }
    for (int o = 32; o > 0; o >>= 1) {
        d1 += __shfl_down(d1, o);
        d2 += __shfl_down(d2, o);
        nf2 += __shfl_down(nf2, o);
    }
    __shared__ float part[4];
    if (lane == 0) {
        float nf = fmaxf(sqrtf(nf2), EPS);
        float nt = fmaxf(norms[cls], EPS);
        float ns = fmaxf(norms[sc], EPS);
        part[wid] = (1.f - d1 / (nf * nt)) + (d2 / (nf * ns)) * simval[cls];
    }
    __syncthreads();
    if (threadIdx.x == 0) fpart[blockIdx.x] = part[0] + part[1] + part[2] + part[3];
}

// one block per sample; C = 1000
__global__ void k_kl(const float* logits, const float* LT, const int* tgt, float* klpart,
                     int B, int C) {
    __shared__ float tl[1000];
    __shared__ float lg[1000];
    __shared__ float red[256];
    int s = blockIdx.x, t = threadIdx.x;
    int cls = tgt[s];
    const float* ltr = LT + (long)cls * C;
    const float* lgr = logits + (long)s * C;
    float m1 = -INFINITY, m2 = -INFINITY;
    for (int j = t; j < C; j += 256) {
        float a = ltr[j], b = lgr[j];
        tl[j] = a;
        lg[j] = b;
        m1 = fmaxf(m1, a);
        m2 = fmaxf(m2, b);
    }
    __syncthreads();
    m1 = block_max(m1, red);
    m2 = block_max(m2, red);
    float e[4];
    float s1 = 0.f, s2 = 0.f;
#pragma unroll
    for (int i = 0; i < 4; i++) {
        int j = t + i * 256;
        if (j < C) {
            e[i] = expf(tl[j] - m1);
            s1 += e[i];
            s2 += expf(lg[j] - m2);
        } else {
            e[i] = 0.f;
        }
    }
    s1 = block_sum(s1, red);
    s2 = block_sum(s2, red);
    float ls1 = logf(s1), ls2 = logf(s2);
    float kl = 0.f;
#pragma unroll
    for (int i = 0; i < 4; i++) {
        int j = t + i * 256;
        if (j < C) {
            float p = e[i] / s1;
            float lp = tl[j] - m1 - ls1;
            float lq = lg[j] - m2 - ls2;
            kl += p * (lp - lq);
        }
    }
    kl = block_sum(kl, red);
    if (t == 0) klpart[s] = kl;
}

__global__ void k_final(const float* fpart, const float* klpart, float* out, int nf, int nk) {
    __shared__ float red[256];
    float a = 0.f;
    for (int i = threadIdx.x; i < nf; i += 256) a += fpart[i];
    a = block_sum(a, red);
    float b = 0.f;
    for (int i = threadIdx.x; i < nk; i += 256) b += klpart[i];
    b = block_sum(b, red);
    if (threadIdx.x == 0) {
        out[0] = a;
        out[1] = b;
    }
}

extern "C" void kernel_launch(void* const* d_in, const int* in_sizes, int n_in,
                              void* d_out, int out_size, void* d_ws, size_t ws_size,
                              hipStream_t stream) {
    const float* feature = (const float*)d_in[0];
    const float* logits  = (const float*)d_in[1];
    const int*   targets = (const int*)d_in[2];
    const float* finit   = (const float*)d_in[3];
    const float* linit   = (const float*)d_in[4];

    const int B = in_sizes[2];                 // 16384
    const int D = in_sizes[0] / B;             // 1024
    const int C = in_sizes[3] / D;             // 1000

    float* out = (float*)d_out;
    float* ftab = out + 2;                     // [C, D]
    float* ltab = out + 2 + (long)C * D;       // [C, C]  (also used as S scratch)

    char* ws = (char*)d_ws;
    int*      counts  = (int*)(ws + 0);        // 1024
    int*      offsets = (int*)(ws + 4096);     // 1024
    int*      cursors = (int*)(ws + 8192);     // 1024
    int*      idx     = (int*)(ws + 12288);    // 16384
    float*    norms   = (float*)(ws + 77824);  // 1024
    float*    simval  = (float*)(ws + 81920);  // 1024
    int*      simcls  = (int*)(ws + 86016);    // 1024
    unsigned* minmax  = (unsigned*)(ws + 90112); // 2
    float*    fpart   = (float*)(ws + 90368);  // 4096
    float*    klpart  = (float*)(ws + 106752); // 16384

    k_init<<<4, 256, 0, stream>>>(counts, cursors, minmax, C);
    k_hist<<<(B + 255) / 256, 256, 0, stream>>>(targets, counts, B);
    k_prefix<<<1, 1024, 0, stream>>>(counts, offsets, C);
    k_scatter<<<(B + 255) / 256, 256, 0, stream>>>(targets, offsets, cursors, idx, B);
    k_sortlists<<<4, 256, 0, stream>>>(counts, offsets, idx, C);

    k_ftab<<<C, 256, 0, stream>>>(feature, finit, counts, offsets, idx, ftab, C, D);
    k_norms<<<C, 256, 0, stream>>>(ftab, norms, C, D);

    dim3 ggrid((C + 63) / 64, (C + 63) / 64);
    k_gemm<<<ggrid, 256, 0, stream>>>(ftab, norms, ltab /*S scratch*/, minmax, C, D);
    k_rowmax<<<C, 256, 0, stream>>>(ltab /*S*/, minmax, simval, simcls, C);

    // now overwrite the S scratch with the real logit_table
    k_ltab<<<C, 256, 0, stream>>>(logits, linit, counts, offsets, idx, ltab, C, C);

    k_floss<<<B / 4, 256, 0, stream>>>(feature, ftab, norms, targets, simval, simcls, fpart, B, D);
    k_kl<<<B, 256, 0, stream>>>(logits, ltab, targets, klpart, B, C);
    k_final<<<1, 256, 0, stream>>>(fpart, klpart, out, B / 4, B);
}

// Round 2
// 317.528 us; speedup vs baseline: 1.2409x; 1.2409x over previous
//
#include <hip/hip_runtime.h>
#include <hip/hip_bf16.h>
#include <math.h>

#define EPS 1e-8f

// ---------- helpers ----------
__device__ __forceinline__ unsigned fenc(float f) {
    unsigned u = __float_as_uint(f);
    return (u & 0x80000000u) ? ~u : (u | 0x80000000u);
}
__device__ __forceinline__ float fdec(unsigned e) {
    unsigned u = (e & 0x80000000u) ? (e & 0x7FFFFFFFu) : ~e;
    return __uint_as_float(u);
}

__device__ __forceinline__ float block_sum(float v, float* red) {
    red[threadIdx.x] = v;
    __syncthreads();
    for (int k = 128; k > 0; k >>= 1) {
        if (threadIdx.x < k) red[threadIdx.x] += red[threadIdx.x + k];
        __syncthreads();
    }
    float r = red[0];
    __syncthreads();
    return r;
}

// ---------- kernels ----------
__global__ void k_init(int* counts, int* cursors, unsigned* minmax, int C) {
    int i = blockIdx.x * blockDim.x + threadIdx.x;
    if (i < C) { counts[i] = 0; cursors[i] = 0; }
    if (i == 0) { minmax[0] = 0xFFFFFFFFu; minmax[1] = 0u; }
}

__global__ void k_hist(const int* tgt, int* counts, int B) {
    int i = blockIdx.x * blockDim.x + threadIdx.x;
    if (i < B) atomicAdd(&counts[tgt[i]], 1);
}

__global__ void k_prefix(const int* counts, int* offsets, int C) {
    __shared__ int buf[1024];
    int t = threadIdx.x;
    int v0 = (t < C) ? counts[t] : 0;
    buf[t] = v0;
    __syncthreads();
    for (int off = 1; off < 1024; off <<= 1) {
        int v = (t >= off) ? buf[t - off] : 0;
        __syncthreads();
        buf[t] += v;
        __syncthreads();
    }
    if (t < C) offsets[t] = buf[t] - v0;
}

__global__ void k_scatter(const int* tgt, const int* offsets, int* cursors, int* idx, int B) {
    int i = blockIdx.x * blockDim.x + threadIdx.x;
    if (i < B) {
        int t = tgt[i];
        int p = atomicAdd(&cursors[t], 1);
        idx[offsets[t] + p] = i;
    }
}

__global__ void k_sortlists(const int* counts, const int* offsets, int* idx, int C) {
    int c = blockIdx.x * blockDim.x + threadIdx.x;
    if (c >= C) return;
    int o = offsets[c], n = counts[c];
    for (int i = 1; i < n; i++) {
        int v = idx[o + i];
        int j = i - 1;
        while (j >= 0 && idx[o + j] > v) { idx[o + j + 1] = idx[o + j]; j--; }
        idx[o + j + 1] = v;
    }
}

// one block (256 thr) per class; D = 1024
__global__ void k_ftab(const float* feat, const float* finit, const int* counts,
                       const int* offsets, const int* idx, float* ftab, int C, int D) {
    int c = blockIdx.x, t = threadIdx.x;
    int n = counts[c];
    if (n == 0) {
        for (int d = t; d < D; d += 256) ftab[(long)c * D + d] = finit[(long)c * D + d];
        return;
    }
    float acc[4] = {0.f, 0.f, 0.f, 0.f};
    int o = offsets[c];
    for (int i = 0; i < n; i++) {
        const float* row = feat + (long)idx[o + i] * D;
#pragma unroll
        for (int j = 0; j < 4; j++) acc[j] += row[t + j * 256];
    }
    float inv = 1.0f / (float)n;
#pragma unroll
    for (int j = 0; j < 4; j++) ftab[(long)c * D + t + j * 256] = acc[j] * inv;
}

// one block per class; C2 = 1000 columns
__global__ void k_ltab(const float* logits, const float* linit, const int* counts,
                       const int* offsets, const int* idx, float* ltab, int C, int C2) {
    int c = blockIdx.x, t = threadIdx.x;
    int n = counts[c];
    if (n == 0) {
        for (int d = t; d < C2; d += 256) ltab[(long)c * C2 + d] = linit[(long)c * C2 + d];
        return;
    }
    float acc[4] = {0.f, 0.f, 0.f, 0.f};
    int o = offsets[c];
    for (int i = 0; i < n; i++) {
        const float* row = logits + (long)idx[o + i] * C2;
#pragma unroll
        for (int j = 0; j < 4; j++) {
            int d = t + j * 256;
            if (d < C2) acc[j] += row[d];
        }
    }
    float inv = 1.0f / (float)n;
#pragma unroll
    for (int j = 0; j < 4; j++) {
        int d = t + j * 256;
        if (d < C2) ltab[(long)c * C2 + d] = acc[j] * inv;
    }
}

__global__ void k_norms(const float* ftab, float* norms, int C, int D) {
    __shared__ float red[256];
    int c = blockIdx.x;
    float s = 0.f;
    for (int d = threadIdx.x; d < D; d += 256) {
        float v = ftab[(long)c * D + d];
        s += v * v;
    }
    s = block_sum(s, red);
    if (threadIdx.x == 0) norms[c] = sqrtf(s);
}

// S = (A A^T) / outer(norms)
// 64x64 tile / block, 256 thr, 4x4 per thread, BK=32, K-major LDS, outer product.
__global__ __launch_bounds__(256) void k_gemm(const float* A, const float* norms, float* S,
                                              unsigned* minmax, int C, int D) {
    __shared__ __align__(16) float As[32][68];  // [k][r], rows 272B (16B-aligned strides)
    __shared__ __align__(16) float Bs[32][68];
    int t = threadIdx.x;
    int tx = t % 16, ty = t / 16;
    int rb = blockIdx.y * 64, cb = blockIdx.x * 64;
    int lr = t >> 3;        // 0..31 (staging row, two halves)
    int la = t & 7;         // 0..7  (staging k-lane)
    float acc[4][4] = {};
    for (int k0 = 0; k0 < D; k0 += 32) {
#pragma unroll
        for (int half = 0; half < 2; half++) {
            int r = lr + half * 32;
            int ga = rb + r, gb = cb + r;
            const float* arow = A + (long)ga * D + k0;
            const float* brow = A + (long)gb * D + k0;
            bool okA = ga < C, okB = gb < C;
#pragma unroll
            for (int j = 0; j < 4; j++) {
                int k = la + 8 * j;     // lanes 0..7 read consecutive dwords
                As[k][r] = okA ? arow[k] : 0.f;
                Bs[k][r] = okB ? brow[k] : 0.f;
            }
        }
        __syncthreads();
#pragma unroll
        for (int k = 0; k < 32; k++) {
            float4 a4 = *reinterpret_cast<const float4*>(&As[k][ty * 4]);
            float4 b4 = *reinterpret_cast<const float4*>(&Bs[k][tx * 4]);
            float a[4] = {a4.x, a4.y, a4.z, a4.w};
            float b[4] = {b4.x, b4.y, b4.z, b4.w};
#pragma unroll
            for (int i = 0; i < 4; i++)
#pragma unroll
                for (int j = 0; j < 4; j++) acc[i][j] += a[i] * b[j];
        }
        __syncthreads();
    }
    float lmin = INFINITY, lmax = -INFINITY;
    float nr[4], nc[4];
#pragma unroll
    for (int i = 0; i < 4; i++) {
        int r = rb + ty * 4 + i;
        nr[i] = (r < C) ? norms[r] : 1.f;
        int cc = cb + tx * 4 + i;
        nc[i] = (cc < C) ? norms[cc] : 1.f;
    }
#pragma unroll
    for (int i = 0; i < 4; i++) {
        int r = rb + ty * 4 + i;
        if (r >= C) continue;
#pragma unroll
        for (int j = 0; j < 4; j++) {
            int cc = cb + tx * 4 + j;
            if (cc >= C) continue;
            float v = acc[i][j] / (nr[i] * nc[j]);
            S[(long)r * C + cc] = v;
            lmin = fminf(lmin, v);
            lmax = fmaxf(lmax, v);
        }
    }
    __shared__ float rmin[256], rmax[256];
    rmin[t] = lmin;
    rmax[t] = lmax;
    __syncthreads();
    for (int k = 128; k > 0; k >>= 1) {
        if (t < k) {
            rmin[t] = fminf(rmin[t], rmin[t + k]);
            rmax[t] = fmaxf(rmax[t], rmax[t + k]);
        }
        __syncthreads();
    }
    if (t == 0) {
        atomicMin(&minmax[0], fenc(rmin[0]));
        atomicMax(&minmax[1], fenc(rmax[0]));
    }
}

// per-row max/argmax excluding diagonal; normalize with cmin/cmax
__global__ void k_rowmax(const float* S, const unsigned* minmax, float* simval, int* simcls, int C) {
    __shared__ float rv[256];
    __shared__ int ri[256];
    int c = blockIdx.x, t = threadIdx.x;
    float best = -INFINITY;
    int bi = 0x7FFFFFFF;
    for (int j = t; j < C; j += 256) {
        if (j == c) continue;
        float v = S[(long)c * C + j];
        if (v > best) { best = v; bi = j; }
    }
    rv[t] = best;
    ri[t] = bi;
    __syncthreads();
    for (int k = 128; k > 0; k >>= 1) {
        if (t < k) {
            if (rv[t + k] > rv[t] || (rv[t + k] == rv[t] && ri[t + k] < ri[t])) {
                rv[t] = rv[t + k];
                ri[t] = ri[t + k];
            }
        }
        __syncthreads();
    }
    if (t == 0) {
        float cmin = fdec(minmax[0]);
        float cmax = fdec(minmax[1]);
        simval[c] = (rv[0] - cmin) / (cmax - cmin);
        simcls[c] = ri[0];
    }
}

// one wave per sample; 4 samples per block
__global__ void k_floss(const float* feat, const float* ftab, const float* norms, const int* tgt,
                        const float* simval, const int* simcls, float* fpart, int B, int D) {
    int wid = threadIdx.x >> 6, lane = threadIdx.x & 63;
    int s = blockIdx.x * 4 + wid;
    int cls = tgt[s];
    int sc = simcls[cls];
    const float* f = feat + (long)s * D;
    const float* ft = ftab + (long)cls * D;
    const float* fs = ftab + (long)sc * D;
    float d1 = 0.f, d2 = 0.f, nf2 = 0.f;
    for (int j = lane; j < D; j += 64) {
        float x = f[j];
        d1 += x * ft[j];
        d2 += x * fs[j];
        nf2 += x * x;
    }
    for (int o = 32; o > 0; o >>= 1) {
        d1 += __shfl_down(d1, o);
        d2 += __shfl_down(d2, o);
        nf2 += __shfl_down(nf2, o);
    }
    __shared__ float part[4];
    if (lane == 0) {
        float nf = fmaxf(sqrtf(nf2), EPS);
        float nt = fmaxf(norms[cls], EPS);
        float ns = fmaxf(norms[sc], EPS);
        part[wid] = (1.f - d1 / (nf * nt)) + (d2 / (nf * ns)) * simval[cls];
    }
    __syncthreads();
    if (threadIdx.x == 0) fpart[blockIdx.x] = part[0] + part[1] + part[2] + part[3];
}

// one WAVE per sample; 4 samples per block; all-register, shuffle reductions. C = 1000.
__global__ __launch_bounds__(256) void k_kl(const float* logits, const float* LT, const int* tgt,
                                            float* klpart, int B, int C) {
    int wid = threadIdx.x >> 6, lane = threadIdx.x & 63;
    int s = blockIdx.x * 4 + wid;
    int cls = tgt[s];
    const float* a = LT + (long)cls * C;
    const float* b = logits + (long)s * C;
    float ta[16], tb[16];
    float m1 = -INFINITY, m2 = -INFINITY;
#pragma unroll
    for (int i = 0; i < 16; i++) {
        int j = lane + (i << 6);
        if (j < C) {
            ta[i] = a[j];
            tb[i] = b[j];
            m1 = fmaxf(m1, ta[i]);
            m2 = fmaxf(m2, tb[i]);
        } else {
            ta[i] = -INFINITY;
            tb[i] = -INFINITY;
        }
    }
#pragma unroll
    for (int o = 32; o > 0; o >>= 1) {
        m1 = fmaxf(m1, __shfl_xor(m1, o));
        m2 = fmaxf(m2, __shfl_xor(m2, o));
    }
    float e1[16];
    float s1 = 0.f, s2 = 0.f;
#pragma unroll
    for (int i = 0; i < 16; i++) {
        int j = lane + (i << 6);
        if (j < C) {
            e1[i] = expf(ta[i] - m1);
            s1 += e1[i];
            s2 += expf(tb[i] - m2);
        } else {
            e1[i] = 0.f;
        }
    }
#pragma unroll
    for (int o = 32; o > 0; o >>= 1) {
        s1 += __shfl_xor(s1, o);
        s2 += __shfl_xor(s2, o);
    }
    float ls1 = logf(s1), ls2 = logf(s2);
    float inv = 1.f / s1;
    float kl = 0.f;
#pragma unroll
    for (int i = 0; i < 16; i++) {
        int j = lane + (i << 6);
        if (j < C) {
            float lp = ta[i] - m1 - ls1;
            float lq = tb[i] - m2 - ls2;
            kl += e1[i] * inv * (lp - lq);
        }
    }
#pragma unroll
    for (int o = 32; o > 0; o >>= 1) kl += __shfl_xor(kl, o);
    if (lane == 0) klpart[s] = kl;
}

__global__ void k_final(const float* fpart, const float* klpart, float* out, int nf, int nk) {
    __shared__ float red[256];
    float a = 0.f;
    for (int i = threadIdx.x; i < nf; i += 256) a += fpart[i];
    a = block_sum(a, red);
    float b = 0.f;
    for (int i = threadIdx.x; i < nk; i += 256) b += klpart[i];
    b = block_sum(b, red);
    if (threadIdx.x == 0) {
        out[0] = a;
        out[1] = b;
    }
}

extern "C" void kernel_launch(void* const* d_in, const int* in_sizes, int n_in,
                              void* d_out, int out_size, void* d_ws, size_t ws_size,
                              hipStream_t stream) {
    const float* feature = (const float*)d_in[0];
    const float* logits  = (const float*)d_in[1];
    const int*   targets = (const int*)d_in[2];
    const float* finit   = (const float*)d_in[3];
    const float* linit   = (const float*)d_in[4];

    const int B = in_sizes[2];                 // 16384
    const int D = in_sizes[0] / B;             // 1024
    const int C = in_sizes[3] / D;             // 1000

    float* out = (float*)d_out;
    float* ftab = out + 2;                     // [C, D]
    float* ltab = out + 2 + (long)C * D;       // [C, C]  (also used as S scratch)

    char* ws = (char*)d_ws;
    int*      counts  = (int*)(ws + 0);        // 1024
    int*      offsets = (int*)(ws + 4096);     // 1024
    int*      cursors = (int*)(ws + 8192);     // 1024
    int*      idx     = (int*)(ws + 12288);    // 16384
    float*    norms   = (float*)(ws + 77824);  // 1024
    float*    simval  = (float*)(ws + 81920);  // 1024
    int*      simcls  = (int*)(ws + 86016);    // 1024
    unsigned* minmax  = (unsigned*)(ws + 90112); // 2
    float*    fpart   = (float*)(ws + 90368);  // 4096
    float*    klpart  = (float*)(ws + 106752); // 16384

    k_init<<<4, 256, 0, stream>>>(counts, cursors, minmax, C);
    k_hist<<<(B + 255) / 256, 256, 0, stream>>>(targets, counts, B);
    k_prefix<<<1, 1024, 0, stream>>>(counts, offsets, C);
    k_scatter<<<(B + 255) / 256, 256, 0, stream>>>(targets, offsets, cursors, idx, B);
    k_sortlists<<<4, 256, 0, stream>>>(counts, offsets, idx, C);

    k_ftab<<<C, 256, 0, stream>>>(feature, finit, counts, offsets, idx, ftab, C, D);
    k_norms<<<C, 256, 0, stream>>>(ftab, norms, C, D);

    dim3 ggrid((C + 63) / 64, (C + 63) / 64);
    k_gemm<<<ggrid, 256, 0, stream>>>(ftab, norms, ltab /*S scratch*/, minmax, C, D);
    k_rowmax<<<C, 256, 0, stream>>>(ltab /*S*/, minmax, simval, simcls, C);

    // now overwrite the S scratch with the real logit_table
    k_ltab<<<C, 256, 0, stream>>>(logits, linit, counts, offsets, idx, ltab, C, C);

    k_floss<<<B / 4, 256, 0, stream>>>(feature, ftab, norms, targets, simval, simcls, fpart, B, D);
    k_kl<<<B / 4, 256, 0, stream>>>(logits, ltab, targets, klpart, B, C);
    k_final<<<1, 256, 0, stream>>>(fpart, klpart, out, B / 4, B);
}

// Round 3
// 284.546 us; speedup vs baseline: 1.3847x; 1.1159x over previous
//
#include <hip/hip_runtime.h>
#include <hip/hip_bf16.h>
#include <math.h>

#define EPS 1e-8f

// ---------- helpers ----------
__device__ __forceinline__ unsigned fenc(float f) {
    unsigned u = __float_as_uint(f);
    return (u & 0x80000000u) ? ~u : (u | 0x80000000u);
}
__device__ __forceinline__ float fdec(unsigned e) {
    unsigned u = (e & 0x80000000u) ? (e & 0x7FFFFFFFu) : ~e;
    return __uint_as_float(u);
}

__device__ __forceinline__ float block_sum(float v, float* red) {
    red[threadIdx.x] = v;
    __syncthreads();
    for (int k = 128; k > 0; k >>= 1) {
        if (threadIdx.x < k) red[threadIdx.x] += red[threadIdx.x + k];
        __syncthreads();
    }
    float r = red[0];
    __syncthreads();
    return r;
}

// ---------- kernels ----------
__global__ void k_init(int* counts, int* cursors, unsigned* minmax, int C) {
    int i = blockIdx.x * blockDim.x + threadIdx.x;
    if (i < C) { counts[i] = 0; cursors[i] = 0; }
    if (i == 0) { minmax[0] = 0xFFFFFFFFu; minmax[1] = 0u; }
}

__global__ void k_hist(const int* tgt, int* counts, int B) {
    int i = blockIdx.x * blockDim.x + threadIdx.x;
    if (i < B) atomicAdd(&counts[tgt[i]], 1);
}

__global__ void k_prefix(const int* counts, int* offsets, int C) {
    __shared__ int buf[1024];
    int t = threadIdx.x;
    int v0 = (t < C) ? counts[t] : 0;
    buf[t] = v0;
    __syncthreads();
    for (int off = 1; off < 1024; off <<= 1) {
        int v = (t >= off) ? buf[t - off] : 0;
        __syncthreads();
        buf[t] += v;
        __syncthreads();
    }
    if (t < C) offsets[t] = buf[t] - v0;
}

__global__ void k_scatter(const int* tgt, const int* offsets, int* cursors, int* idx, int B) {
    int i = blockIdx.x * blockDim.x + threadIdx.x;
    if (i < B) {
        int t = tgt[i];
        int p = atomicAdd(&cursors[t], 1);
        idx[offsets[t] + p] = i;
    }
}

__global__ void k_sortlists(const int* counts, const int* offsets, int* idx, int C) {
    int c = blockIdx.x * blockDim.x + threadIdx.x;
    if (c >= C) return;
    int o = offsets[c], n = counts[c];
    for (int i = 1; i < n; i++) {
        int v = idx[o + i];
        int j = i - 1;
        while (j >= 0 && idx[o + j] > v) { idx[o + j + 1] = idx[o + j]; j--; }
        idx[o + j + 1] = v;
    }
}

// one block (256 thr) per class; D = 1024 (256 float4)
__global__ void k_ftab(const float* feat, const float* finit, const int* counts,
                       const int* offsets, const int* idx, float* ftab, int C, int D) {
    int c = blockIdx.x, t = threadIdx.x;
    int n = counts[c];
    if (n == 0) {
        for (int d = t; d < D; d += 256) ftab[(long)c * D + d] = finit[(long)c * D + d];
        return;
    }
    float4 acc = {0.f, 0.f, 0.f, 0.f};
    int o = offsets[c];
    for (int i = 0; i < n; i++) {
        float4 v = ((const float4*)(feat + (long)idx[o + i] * D))[t];
        acc.x += v.x; acc.y += v.y; acc.z += v.z; acc.w += v.w;
    }
    float inv = 1.0f / (float)n;
    float* dst = ftab + (long)c * D + t * 4;   // ftab only 8B-aligned -> scalar writes
    dst[0] = acc.x * inv;
    dst[1] = acc.y * inv;
    dst[2] = acc.z * inv;
    dst[3] = acc.w * inv;
}

// one block per class; C2 = 1000 columns
__global__ void k_ltab(const float* logits, const float* linit, const int* counts,
                       const int* offsets, const int* idx, float* ltab, int C, int C2) {
    int c = blockIdx.x, t = threadIdx.x;
    int n = counts[c];
    if (n == 0) {
        for (int d = t; d < C2; d += 256) ltab[(long)c * C2 + d] = linit[(long)c * C2 + d];
        return;
    }
    float acc[4] = {0.f, 0.f, 0.f, 0.f};
    int o = offsets[c];
    for (int i = 0; i < n; i++) {
        const float* row = logits + (long)idx[o + i] * C2;
#pragma unroll
        for (int j = 0; j < 4; j++) {
            int d = t + j * 256;
            if (d < C2) acc[j] += row[d];
        }
    }
    float inv = 1.0f / (float)n;
#pragma unroll
    for (int j = 0; j < 4; j++) {
        int d = t + j * 256;
        if (d < C2) ltab[(long)c * C2 + d] = acc[j] * inv;
    }
}

__global__ void k_norms(const float* ftab, float* norms, int C, int D) {
    __shared__ float red[256];
    int c = blockIdx.x;
    float s = 0.f;
    for (int d = threadIdx.x; d < D; d += 256) {
        float v = ftab[(long)c * D + d];
        s += v * v;
    }
    s = block_sum(s, red);
    if (threadIdx.x == 0) norms[c] = sqrtf(s);
}

// S = (A A^T) / outer(norms)
// 64x64 tile / block, 256 thr, 4x4 per thread, BK=32, K-major LDS.
// ILP: k unrolled by 4 (8 ds_read_b128 in flight), next K-tile reg-prefetched.
__global__ __launch_bounds__(256) void k_gemm(const float* A, const float* norms, float* S,
                                              unsigned* minmax, int C, int D) {
    __shared__ __align__(16) float As[32][68];
    __shared__ __align__(16) float Bs[32][68];
    int t = threadIdx.x;
    int tx = t % 16, ty = t / 16;
    int rb = blockIdx.y * 64, cb = blockIdx.x * 64;
    int lr = t >> 3;        // 0..31
    int la = t & 7;         // 0..7
    int r0 = lr, r1 = lr + 32;
    int ga0 = rb + r0, ga1 = rb + r1, gb0 = cb + r0, gb1 = cb + r1;
    bool okA0 = ga0 < C, okA1 = ga1 < C, okB0 = gb0 < C, okB1 = gb1 < C;
    const float* arow0 = A + (long)ga0 * D;
    const float* arow1 = A + (long)ga1 * D;
    const float* brow0 = A + (long)gb0 * D;
    const float* brow1 = A + (long)gb1 * D;

    float pa0[4], pa1[4], pb0[4], pb1[4];
#define LOADT(K0)                                                          \
    _Pragma("unroll") for (int j = 0; j < 4; j++) {                        \
        int k = (K0) + la + 8 * j;                                         \
        pa0[j] = okA0 ? arow0[k] : 0.f;                                    \
        pa1[j] = okA1 ? arow1[k] : 0.f;                                    \
        pb0[j] = okB0 ? brow0[k] : 0.f;                                    \
        pb1[j] = okB1 ? brow1[k] : 0.f;                                    \
    }

    LOADT(0)
    float acc[4][4] = {};
    for (int step = 0; step < 32; step++) {
        __syncthreads();   // previous compute done before overwriting LDS
#pragma unroll
        for (int j = 0; j < 4; j++) {
            int k = la + 8 * j;
            As[k][r0] = pa0[j];
            As[k][r1] = pa1[j];
            Bs[k][r0] = pb0[j];
            Bs[k][r1] = pb1[j];
        }
        __syncthreads();
        if (step < 31) {
            int k0n = (step + 1) * 32;
            LOADT(k0n)
        }
#pragma unroll
        for (int kk = 0; kk < 32; kk += 4) {
            float4 af[4], bf[4];
#pragma unroll
            for (int u = 0; u < 4; u++) {
                af[u] = *reinterpret_cast<const float4*>(&As[kk + u][ty * 4]);
                bf[u] = *reinterpret_cast<const float4*>(&Bs[kk + u][tx * 4]);
            }
#pragma unroll
            for (int u = 0; u < 4; u++) {
                float a[4] = {af[u].x, af[u].y, af[u].z, af[u].w};
                float b[4] = {bf[u].x, bf[u].y, bf[u].z, bf[u].w};
#pragma unroll
                for (int i = 0; i < 4; i++)
#pragma unroll
                    for (int j = 0; j < 4; j++) acc[i][j] += a[i] * b[j];
            }
        }
    }
#undef LOADT

    float lmin = INFINITY, lmax = -INFINITY;
    float nr[4], nc[4];
#pragma unroll
    for (int i = 0; i < 4; i++) {
        int r = rb + ty * 4 + i;
        nr[i] = (r < C) ? norms[r] : 1.f;
        int cc = cb + tx * 4 + i;
        nc[i] = (cc < C) ? norms[cc] : 1.f;
    }
#pragma unroll
    for (int i = 0; i < 4; i++) {
        int r = rb + ty * 4 + i;
        if (r >= C) continue;
#pragma unroll
        for (int j = 0; j < 4; j++) {
            int cc = cb + tx * 4 + j;
            if (cc >= C) continue;
            float v = acc[i][j] / (nr[i] * nc[j]);
            S[(long)r * C + cc] = v;
            lmin = fminf(lmin, v);
            lmax = fmaxf(lmax, v);
        }
    }
    __shared__ float rmin[256], rmax[256];
    rmin[t] = lmin;
    rmax[t] = lmax;
    __syncthreads();
    for (int k = 128; k > 0; k >>= 1) {
        if (t < k) {
            rmin[t] = fminf(rmin[t], rmin[t + k]);
            rmax[t] = fmaxf(rmax[t], rmax[t + k]);
        }
        __syncthreads();
    }
    if (t == 0) {
        atomicMin(&minmax[0], fenc(rmin[0]));
        atomicMax(&minmax[1], fenc(rmax[0]));
    }
}

// per-row max/argmax excluding diagonal; normalize with cmin/cmax
__global__ void k_rowmax(const float* S, const unsigned* minmax, float* simval, int* simcls, int C) {
    __shared__ float rv[256];
    __shared__ int ri[256];
    int c = blockIdx.x, t = threadIdx.x;
    float best = -INFINITY;
    int bi = 0x7FFFFFFF;
    for (int j = t; j < C; j += 256) {
        if (j == c) continue;
        float v = S[(long)c * C + j];
        if (v > best) { best = v; bi = j; }
    }
    rv[t] = best;
    ri[t] = bi;
    __syncthreads();
    for (int k = 128; k > 0; k >>= 1) {
        if (t < k) {
            if (rv[t + k] > rv[t] || (rv[t + k] == rv[t] && ri[t + k] < ri[t])) {
                rv[t] = rv[t + k];
                ri[t] = ri[t + k];
            }
        }
        __syncthreads();
    }
    if (t == 0) {
        float cmin = fdec(minmax[0]);
        float cmax = fdec(minmax[1]);
        simval[c] = (rv[0] - cmin) / (cmax - cmin);
        simcls[c] = ri[0];
    }
}

// one wave per sample; 4 samples per block; vectorized loads
__global__ void k_floss(const float* feat, const float* ftab, const float* norms, const int* tgt,
                        const float* simval, const int* simcls, float* fpart, int B, int D) {
    int wid = threadIdx.x >> 6, lane = threadIdx.x & 63;
    int s = blockIdx.x * 4 + wid;
    int cls = tgt[s];
    int sc = simcls[cls];
    const float4* f4 = (const float4*)(feat + (long)s * D);           // 16B-aligned
    const float2* ft2 = (const float2*)(ftab + (long)cls * D);        // 8B-aligned
    const float2* fs2 = (const float2*)(ftab + (long)sc * D);
    float d1 = 0.f, d2 = 0.f, nf2 = 0.f;
#pragma unroll
    for (int i = 0; i < 4; i++) {
        int j = lane + i * 64;           // float4 index, 0..255
        float4 x = f4[j];
        float2 a0 = ft2[2 * j], a1 = ft2[2 * j + 1];
        float2 b0 = fs2[2 * j], b1 = fs2[2 * j + 1];
        d1 += x.x * a0.x + x.y * a0.y + x.z * a1.x + x.w * a1.y;
        d2 += x.x * b0.x + x.y * b0.y + x.z * b1.x + x.w * b1.y;
        nf2 += x.x * x.x + x.y * x.y + x.z * x.z + x.w * x.w;
    }
    for (int o = 32; o > 0; o >>= 1) {
        d1 += __shfl_down(d1, o);
        d2 += __shfl_down(d2, o);
        nf2 += __shfl_down(nf2, o);
    }
    __shared__ float part[4];
    if (lane == 0) {
        float nf = fmaxf(sqrtf(nf2), EPS);
        float nt = fmaxf(norms[cls], EPS);
        float ns = fmaxf(norms[sc], EPS);
        part[wid] = (1.f - d1 / (nf * nt)) + (d2 / (nf * ns)) * simval[cls];
    }
    __syncthreads();
    if (threadIdx.x == 0) fpart[blockIdx.x] = part[0] + part[1] + part[2] + part[3];
}

// one WAVE per sample; 4 samples per block; all-register, shuffle reductions. C = 1000.
__global__ __launch_bounds__(256) void k_kl(const float* logits, const float* LT, const int* tgt,
                                            float* klpart, int B, int C) {
    int wid = threadIdx.x >> 6, lane = threadIdx.x & 63;
    int s = blockIdx.x * 4 + wid;
    int cls = tgt[s];
    const float* a = LT + (long)cls * C;
    const float* b = logits + (long)s * C;
    float ta[16], tb[16];
    float m1 = -INFINITY, m2 = -INFINITY;
#pragma unroll
    for (int i = 0; i < 16; i++) {
        int j = lane + (i << 6);
        if (j < C) {
            ta[i] = a[j];
            tb[i] = b[j];
            m1 = fmaxf(m1, ta[i]);
            m2 = fmaxf(m2, tb[i]);
        } else {
            ta[i] = -INFINITY;
            tb[i] = -INFINITY;
        }
    }
#pragma unroll
    for (int o = 32; o > 0; o >>= 1) {
        m1 = fmaxf(m1, __shfl_xor(m1, o));
        m2 = fmaxf(m2, __shfl_xor(m2, o));
    }
    float e1[16];
    float s1 = 0.f, s2 = 0.f;
#pragma unroll
    for (int i = 0; i < 16; i++) {
        int j = lane + (i << 6);
        if (j < C) {
            e1[i] = expf(ta[i] - m1);
            s1 += e1[i];
            s2 += expf(tb[i] - m2);
        } else {
            e1[i] = 0.f;
        }
    }
#pragma unroll
    for (int o = 32; o > 0; o >>= 1) {
        s1 += __shfl_xor(s1, o);
        s2 += __shfl_xor(s2, o);
    }
    float ls1 = logf(s1), ls2 = logf(s2);
    float inv = 1.f / s1;
    float kl = 0.f;
#pragma unroll
    for (int i = 0; i < 16; i++) {
        int j = lane + (i << 6);
        if (j < C) {
            float lp = ta[i] - m1 - ls1;
            float lq = tb[i] - m2 - ls2;
            kl += e1[i] * inv * (lp - lq);
        }
    }
#pragma unroll
    for (int o = 32; o > 0; o >>= 1) kl += __shfl_xor(kl, o);
    if (lane == 0) klpart[s] = kl;
}

__global__ void k_final(const float* fpart, const float* klpart, float* out, int nf, int nk) {
    __shared__ float red[256];
    float a = 0.f;
    for (int i = threadIdx.x; i < nf; i += 256) a += fpart[i];
    a = block_sum(a, red);
    float b = 0.f;
    for (int i = threadIdx.x; i < nk; i += 256) b += klpart[i];
    b = block_sum(b, red);
    if (threadIdx.x == 0) {
        out[0] = a;
        out[1] = b;
    }
}

extern "C" void kernel_launch(void* const* d_in, const int* in_sizes, int n_in,
                              void* d_out, int out_size, void* d_ws, size_t ws_size,
                              hipStream_t stream) {
    const float* feature = (const float*)d_in[0];
    const float* logits  = (const float*)d_in[1];
    const int*   targets = (const int*)d_in[2];
    const float* finit   = (const float*)d_in[3];
    const float* linit   = (const float*)d_in[4];

    const int B = in_sizes[2];                 // 16384
    const int D = in_sizes[0] / B;             // 1024
    const int C = in_sizes[3] / D;             // 1000

    float* out = (float*)d_out;
    float* ftab = out + 2;                     // [C, D]
    float* ltab = out + 2 + (long)C * D;       // [C, C]  (also used as S scratch)

    char* ws = (char*)d_ws;
    int*      counts  = (int*)(ws + 0);        // 1024
    int*      offsets = (int*)(ws + 4096);     // 1024
    int*      cursors = (int*)(ws + 8192);     // 1024
    int*      idx     = (int*)(ws + 12288);    // 16384
    float*    norms   = (float*)(ws + 77824);  // 1024
    float*    simval  = (float*)(ws + 81920);  // 1024
    int*      simcls  = (int*)(ws + 86016);    // 1024
    unsigned* minmax  = (unsigned*)(ws + 90112); // 2
    float*    fpart   = (float*)(ws + 90368);  // 4096
    float*    klpart  = (float*)(ws + 106752); // 16384

    k_init<<<4, 256, 0, stream>>>(counts, cursors, minmax, C);
    k_hist<<<(B + 255) / 256, 256, 0, stream>>>(targets, counts, B);
    k_prefix<<<1, 1024, 0, stream>>>(counts, offsets, C);
    k_scatter<<<(B + 255) / 256, 256, 0, stream>>>(targets, offsets, cursors, idx, B);
    k_sortlists<<<4, 256, 0, stream>>>(counts, offsets, idx, C);

    k_ftab<<<C, 256, 0, stream>>>(feature, finit, counts, offsets, idx, ftab, C, D);
    k_norms<<<C, 256, 0, stream>>>(ftab, norms, C, D);

    dim3 ggrid((C + 63) / 64, (C + 63) / 64);
    k_gemm<<<ggrid, 256, 0, stream>>>(ftab, norms, ltab /*S scratch*/, minmax, C, D);
    k_rowmax<<<C, 256, 0, stream>>>(ltab /*S*/, minmax, simval, simcls, C);

    // now overwrite the S scratch with the real logit_table
    k_ltab<<<C, 256, 0, stream>>>(logits, linit, counts, offsets, idx, ltab, C, C);

    k_floss<<<B / 4, 256, 0, stream>>>(feature, ftab, norms, targets, simval, simcls, fpart, B, D);
    k_kl<<<B / 4, 256, 0, stream>>>(logits, ltab, targets, klpart, B, C);
    k_final<<<1, 256, 0, stream>>>(fpart, klpart, out, B / 4, B);
}

// Round 4
// 201.450 us; speedup vs baseline: 1.9559x; 1.4125x over previous
//
#include <hip/hip_runtime.h>
#include <hip/hip_bf16.h>
#include <math.h>

#define EPS 1e-8f

// ---------- helpers ----------
__device__ __forceinline__ unsigned fenc(float f) {
    unsigned u = __float_as_uint(f);
    return (u & 0x80000000u) ? ~u : (u | 0x80000000u);
}
__device__ __forceinline__ float fdec(unsigned e) {
    unsigned u = (e & 0x80000000u) ? (e & 0x7FFFFFFFu) : ~e;
    return __uint_as_float(u);
}

__device__ __forceinline__ float block_sum(float v, float* red) {
    red[threadIdx.x] = v;
    __syncthreads();
    for (int k = 128; k > 0; k >>= 1) {
        if (threadIdx.x < k) red[threadIdx.x] += red[threadIdx.x + k];
        __syncthreads();
    }
    float r = red[0];
    __syncthreads();
    return r;
}

// ---------- kernels ----------
__global__ void k_init(unsigned* minmax) {
    if (threadIdx.x == 0) { minmax[0] = 0xFFFFFFFFu; minmax[1] = 0u; }
}

// per-group histogram: gh[g*1024 + c]
__global__ void k_ghist(const int* tgt, int* gh, int B) {
    __shared__ int lh[1024];
    int g = blockIdx.x, t = threadIdx.x;
    lh[t] = 0; lh[t + 256] = 0; lh[t + 512] = 0; lh[t + 768] = 0;
    __syncthreads();
    int i = g * 256 + t;
    if (i < B) atomicAdd(&lh[tgt[i]], 1);
    __syncthreads();
    int* dst = gh + g * 1024;
    dst[t] = lh[t]; dst[t + 256] = lh[t + 256];
    dst[t + 512] = lh[t + 512]; dst[t + 768] = lh[t + 768];
}

// in-place exclusive scan of gh over groups (per class), totals -> counts,
// class-exclusive-scan -> offsets. One block, 1024 threads.
__global__ void k_bases(int* gh, int* counts, int* offsets, int G, int C) {
    __shared__ int buf[1024];
    int c = threadIdx.x;
    int run = 0;
    for (int g = 0; g < G; g++) {
        int v = gh[g * 1024 + c];
        gh[g * 1024 + c] = run;
        run += v;
    }
    if (c < C) counts[c] = run;
    int v0 = (c < C) ? run : 0;
    buf[c] = v0;
    __syncthreads();
    for (int off = 1; off < 1024; off <<= 1) {
        int v = (c >= off) ? buf[c - off] : 0;
        __syncthreads();
        buf[c] += v;
        __syncthreads();
    }
    if (c < C) offsets[c] = buf[c] - v0;
}

// stable rank within group via LDS compare-count; deterministic idx
__global__ void k_rank_scatter(const int* tgt, const int* offsets, const int* gh,
                               int* idx, int B) {
    __shared__ int lt[256];
    int g = blockIdx.x, t = threadIdx.x;
    int i = g * 256 + t;
    int my = (i < B) ? tgt[i] : -1;
    lt[t] = my;
    __syncthreads();
    if (i < B) {
        int rank = 0;
        for (int j = 0; j < t; j++) rank += (lt[j] == my);
        idx[offsets[my] + gh[g * 1024 + my] + rank] = i;
    }
}

// one block (256 thr) per class; D = 1024 (256 float4)
__global__ void k_ftab(const float* feat, const float* finit, const int* counts,
                       const int* offsets, const int* idx, float* ftab, int C, int D) {
    int c = blockIdx.x, t = threadIdx.x;
    int n = counts[c];
    if (n == 0) {
        for (int d = t; d < D; d += 256) ftab[(long)c * D + d] = finit[(long)c * D + d];
        return;
    }
    float4 acc = {0.f, 0.f, 0.f, 0.f};
    int o = offsets[c];
    for (int i = 0; i < n; i++) {
        float4 v = ((const float4*)(feat + (long)idx[o + i] * D))[t];
        acc.x += v.x; acc.y += v.y; acc.z += v.z; acc.w += v.w;
    }
    float inv = 1.0f / (float)n;
    float* dst = ftab + (long)c * D + t * 4;   // ftab only 8B-aligned -> scalar writes
    dst[0] = acc.x * inv;
    dst[1] = acc.y * inv;
    dst[2] = acc.z * inv;
    dst[3] = acc.w * inv;
}

// one block per class; C2 = 1000 columns (250 float4 per row; rows 16B-aligned)
__global__ void k_ltab(const float* logits, const float* linit, const int* counts,
                       const int* offsets, const int* idx, float* ltab, int C, int C2) {
    int c = blockIdx.x, t = threadIdx.x;
    int n = counts[c];
    if (n == 0) {
        for (int d = t; d < C2; d += 256) ltab[(long)c * C2 + d] = linit[(long)c * C2 + d];
        return;
    }
    int nv = C2 >> 2;                 // 250
    if (t < nv) {
        float4 acc = {0.f, 0.f, 0.f, 0.f};
        int o = offsets[c];
        for (int i = 0; i < n; i++) {
            float4 v = ((const float4*)(logits + (long)idx[o + i] * C2))[t];
            acc.x += v.x; acc.y += v.y; acc.z += v.z; acc.w += v.w;
        }
        float inv = 1.0f / (float)n;
        float* dst = ltab + (long)c * C2 + t * 4;  // 8B-aligned -> scalar writes
        dst[0] = acc.x * inv;
        dst[1] = acc.y * inv;
        dst[2] = acc.z * inv;
        dst[3] = acc.w * inv;
    }
    // tail (C2 % 4) — none for C2=1000? 1000 = 4*250 exactly, no tail.
}

__global__ void k_norms(const float* ftab, float* norms, int C, int D) {
    __shared__ float red[256];
    int c = blockIdx.x;
    float s = 0.f;
    for (int d = threadIdx.x; d < D; d += 256) {
        float v = ftab[(long)c * D + d];
        s += v * v;
    }
    s = block_sum(s, red);
    if (threadIdx.x == 0) norms[c] = sqrtf(s);
}

// S = (A A^T) / outer(norms)
// 64x64 tile / block, 256 thr, 4x4 per thread, BK=32, K-major LDS.
__global__ __launch_bounds__(256) void k_gemm(const float* A, const float* norms, float* S,
                                              unsigned* minmax, int C, int D) {
    __shared__ __align__(16) float As[32][68];
    __shared__ __align__(16) float Bs[32][68];
    int t = threadIdx.x;
    int tx = t % 16, ty = t / 16;
    int rb = blockIdx.y * 64, cb = blockIdx.x * 64;
    int lr = t >> 3;        // 0..31
    int la = t & 7;         // 0..7
    int r0 = lr, r1 = lr + 32;
    int ga0 = rb + r0, ga1 = rb + r1, gb0 = cb + r0, gb1 = cb + r1;
    bool okA0 = ga0 < C, okA1 = ga1 < C, okB0 = gb0 < C, okB1 = gb1 < C;
    const float* arow0 = A + (long)ga0 * D;
    const float* arow1 = A + (long)ga1 * D;
    const float* brow0 = A + (long)gb0 * D;
    const float* brow1 = A + (long)gb1 * D;

    float pa0[4], pa1[4], pb0[4], pb1[4];
#define LOADT(K0)                                                          \
    _Pragma("unroll") for (int j = 0; j < 4; j++) {                        \
        int k = (K0) + la + 8 * j;                                         \
        pa0[j] = okA0 ? arow0[k] : 0.f;                                    \
        pa1[j] = okA1 ? arow1[k] : 0.f;                                    \
        pb0[j] = okB0 ? brow0[k] : 0.f;                                    \
        pb1[j] = okB1 ? brow1[k] : 0.f;                                    \
    }

    LOADT(0)
    float acc[4][4] = {};
    for (int step = 0; step < 32; step++) {
        __syncthreads();
#pragma unroll
        for (int j = 0; j < 4; j++) {
            int k = la + 8 * j;
            As[k][r0] = pa0[j];
            As[k][r1] = pa1[j];
            Bs[k][r0] = pb0[j];
            Bs[k][r1] = pb1[j];
        }
        __syncthreads();
        if (step < 31) {
            int k0n = (step + 1) * 32;
            LOADT(k0n)
        }
#pragma unroll
        for (int kk = 0; kk < 32; kk += 4) {
            float4 af[4], bf[4];
#pragma unroll
            for (int u = 0; u < 4; u++) {
                af[u] = *reinterpret_cast<const float4*>(&As[kk + u][ty * 4]);
                bf[u] = *reinterpret_cast<const float4*>(&Bs[kk + u][tx * 4]);
            }
#pragma unroll
            for (int u = 0; u < 4; u++) {
                float a[4] = {af[u].x, af[u].y, af[u].z, af[u].w};
                float b[4] = {bf[u].x, bf[u].y, bf[u].z, bf[u].w};
#pragma unroll
                for (int i = 0; i < 4; i++)
#pragma unroll
                    for (int j = 0; j < 4; j++) acc[i][j] += a[i] * b[j];
            }
        }
    }
#undef LOADT

    float lmin = INFINITY, lmax = -INFINITY;
    float nr[4], nc[4];
#pragma unroll
    for (int i = 0; i < 4; i++) {
        int r = rb + ty * 4 + i;
        nr[i] = (r < C) ? norms[r] : 1.f;
        int cc = cb + tx * 4 + i;
        nc[i] = (cc < C) ? norms[cc] : 1.f;
    }
#pragma unroll
    for (int i = 0; i < 4; i++) {
        int r = rb + ty * 4 + i;
        if (r >= C) continue;
#pragma unroll
        for (int j = 0; j < 4; j++) {
            int cc = cb + tx * 4 + j;
            if (cc >= C) continue;
            float v = acc[i][j] / (nr[i] * nc[j]);
            S[(long)r * C + cc] = v;
            lmin = fminf(lmin, v);
            lmax = fmaxf(lmax, v);
        }
    }
    __shared__ float rmin[256], rmax[256];
    rmin[t] = lmin;
    rmax[t] = lmax;
    __syncthreads();
    for (int k = 128; k > 0; k >>= 1) {
        if (t < k) {
            rmin[t] = fminf(rmin[t], rmin[t + k]);
            rmax[t] = fmaxf(rmax[t], rmax[t + k]);
        }
        __syncthreads();
    }
    if (t == 0) {
        atomicMin(&minmax[0], fenc(rmin[0]));
        atomicMax(&minmax[1], fenc(rmax[0]));
    }
}

// per-row max/argmax excluding diagonal; normalize with cmin/cmax
__global__ void k_rowmax(const float* S, const unsigned* minmax, float* simval, int* simcls, int C) {
    __shared__ float rv[256];
    __shared__ int ri[256];
    int c = blockIdx.x, t = threadIdx.x;
    float best = -INFINITY;
    int bi = 0x7FFFFFFF;
    for (int j = t; j < C; j += 256) {
        if (j == c) continue;
        float v = S[(long)c * C + j];
        if (v > best) { best = v; bi = j; }
    }
    rv[t] = best;
    ri[t] = bi;
    __syncthreads();
    for (int k = 128; k > 0; k >>= 1) {
        if (t < k) {
            if (rv[t + k] > rv[t] || (rv[t + k] == rv[t] && ri[t + k] < ri[t])) {
                rv[t] = rv[t + k];
                ri[t] = ri[t + k];
            }
        }
        __syncthreads();
    }
    if (t == 0) {
        float cmin = fdec(minmax[0]);
        float cmax = fdec(minmax[1]);
        simval[c] = (rv[0] - cmin) / (cmax - cmin);
        simcls[c] = ri[0];
    }
}

// one wave per sample; 4 samples per block; vectorized loads
__global__ void k_floss(const float* feat, const float* ftab, const float* norms, const int* tgt,
                        const float* simval, const int* simcls, float* fpart, int B, int D) {
    int wid = threadIdx.x >> 6, lane = threadIdx.x & 63;
    int s = blockIdx.x * 4 + wid;
    int cls = tgt[s];
    int sc = simcls[cls];
    const float4* f4 = (const float4*)(feat + (long)s * D);           // 16B-aligned
    const float2* ft2 = (const float2*)(ftab + (long)cls * D);        // 8B-aligned
    const float2* fs2 = (const float2*)(ftab + (long)sc * D);
    float d1 = 0.f, d2 = 0.f, nf2 = 0.f;
#pragma unroll
    for (int i = 0; i < 4; i++) {
        int j = lane + i * 64;           // float4 index, 0..255
        float4 x = f4[j];
        float2 a0 = ft2[2 * j], a1 = ft2[2 * j + 1];
        float2 b0 = fs2[2 * j], b1 = fs2[2 * j + 1];
        d1 += x.x * a0.x + x.y * a0.y + x.z * a1.x + x.w * a1.y;
        d2 += x.x * b0.x + x.y * b0.y + x.z * b1.x + x.w * b1.y;
        nf2 += x.x * x.x + x.y * x.y + x.z * x.z + x.w * x.w;
    }
    for (int o = 32; o > 0; o >>= 1) {
        d1 += __shfl_down(d1, o);
        d2 += __shfl_down(d2, o);
        nf2 += __shfl_down(nf2, o);
    }
    __shared__ float part[4];
    if (lane == 0) {
        float nf = fmaxf(sqrtf(nf2), EPS);
        float nt = fmaxf(norms[cls], EPS);
        float ns = fmaxf(norms[sc], EPS);
        part[wid] = (1.f - d1 / (nf * nt)) + (d2 / (nf * ns)) * simval[cls];
    }
    __syncthreads();
    if (threadIdx.x == 0) fpart[blockIdx.x] = part[0] + part[1] + part[2] + part[3];
}

// one WAVE per sample; 4 samples per block; float2 loads, shuffle reductions. C even.
__global__ __launch_bounds__(256) void k_kl(const float* logits, const float* LT, const int* tgt,
                                            float* klpart, int B, int C) {
    int wid = threadIdx.x >> 6, lane = threadIdx.x & 63;
    int s = blockIdx.x * 4 + wid;
    int cls = tgt[s];
    const float2* a2 = (const float2*)(LT + (long)cls * C);      // 8B-aligned
    const float2* b2 = (const float2*)(logits + (long)s * C);    // 16B-aligned
    int H = C >> 1;   // 500
    float ta[16], tb[16];
    float m1 = -INFINITY, m2 = -INFINITY;
#pragma unroll
    for (int p = 0; p < 8; p++) {
        int j = lane + (p << 6);
        if (j < H) {
            float2 va = a2[j], vb = b2[j];
            ta[2 * p] = va.x; ta[2 * p + 1] = va.y;
            tb[2 * p] = vb.x; tb[2 * p + 1] = vb.y;
            m1 = fmaxf(m1, fmaxf(va.x, va.y));
            m2 = fmaxf(m2, fmaxf(vb.x, vb.y));
        } else {
            ta[2 * p] = -INFINITY; ta[2 * p + 1] = -INFINITY;
            tb[2 * p] = -INFINITY; tb[2 * p + 1] = -INFINITY;
        }
    }
#pragma unroll
    for (int o = 32; o > 0; o >>= 1) {
        m1 = fmaxf(m1, __shfl_xor(m1, o));
        m2 = fmaxf(m2, __shfl_xor(m2, o));
    }
    float e1[16];
    float s1 = 0.f, s2 = 0.f;
#pragma unroll
    for (int i = 0; i < 16; i++) {
        int j = lane + ((i >> 1) << 6);
        if (j < H) {
            e1[i] = expf(ta[i] - m1);
            s1 += e1[i];
            s2 += expf(tb[i] - m2);
        } else {
            e1[i] = 0.f;
        }
    }
#pragma unroll
    for (int o = 32; o > 0; o >>= 1) {
        s1 += __shfl_xor(s1, o);
        s2 += __shfl_xor(s2, o);
    }
    float ls1 = logf(s1), ls2 = logf(s2);
    float inv = 1.f / s1;
    float kl = 0.f;
#pragma unroll
    for (int i = 0; i < 16; i++) {
        int j = lane + ((i >> 1) << 6);
        if (j < H) {
            float lp = ta[i] - m1 - ls1;
            float lq = tb[i] - m2 - ls2;
            kl += e1[i] * inv * (lp - lq);
        }
    }
#pragma unroll
    for (int o = 32; o > 0; o >>= 1) kl += __shfl_xor(kl, o);
    if (lane == 0) klpart[s] = kl;
}

__global__ void k_final(const float* fpart, const float* klpart, float* out, int nf, int nk) {
    __shared__ float red[256];
    float a = 0.f;
    for (int i = threadIdx.x; i < nf; i += 256) a += fpart[i];
    a = block_sum(a, red);
    float b = 0.f;
    for (int i = threadIdx.x; i < nk; i += 256) b += klpart[i];
    b = block_sum(b, red);
    if (threadIdx.x == 0) {
        out[0] = a;
        out[1] = b;
    }
}

extern "C" void kernel_launch(void* const* d_in, const int* in_sizes, int n_in,
                              void* d_out, int out_size, void* d_ws, size_t ws_size,
                              hipStream_t stream) {
    const float* feature = (const float*)d_in[0];
    const float* logits  = (const float*)d_in[1];
    const int*   targets = (const int*)d_in[2];
    const float* finit   = (const float*)d_in[3];
    const float* linit   = (const float*)d_in[4];

    const int B = in_sizes[2];                 // 16384
    const int D = in_sizes[0] / B;             // 1024
    const int C = in_sizes[3] / D;             // 1000

    float* out = (float*)d_out;
    float* ftab = out + 2;                     // [C, D]
    float* ltab = out + 2 + (long)C * D;       // [C, C]  (S scratch + ghist scratch)

    const int G = (B + 255) / 256;             // 64 groups

    char* ws = (char*)d_ws;
    int*      counts  = (int*)(ws + 0);        // 1024
    int*      offsets = (int*)(ws + 4096);     // 1024
    int*      idx     = (int*)(ws + 12288);    // 16384
    float*    norms   = (float*)(ws + 77824);  // 1024
    float*    simval  = (float*)(ws + 81920);  // 1024
    int*      simcls  = (int*)(ws + 86016);    // 1024
    unsigned* minmax  = (unsigned*)(ws + 90112); // 2
    float*    fpart   = (float*)(ws + 90368);  // 4096
    float*    klpart  = (float*)(ws + 106752); // 16384

    // gh scratch lives in the (not-yet-written) ltab output region: G*1024 ints = 256 KB
    int* gh = (int*)ltab;

    k_init<<<1, 64, 0, stream>>>(minmax);
    k_ghist<<<G, 256, 0, stream>>>(targets, gh, B);
    k_bases<<<1, 1024, 0, stream>>>(gh, counts, offsets, G, C);
    k_rank_scatter<<<G, 256, 0, stream>>>(targets, offsets, gh, idx, B);

    k_ftab<<<C, 256, 0, stream>>>(feature, finit, counts, offsets, idx, ftab, C, D);
    k_norms<<<C, 256, 0, stream>>>(ftab, norms, C, D);

    dim3 ggrid((C + 63) / 64, (C + 63) / 64);
    k_gemm<<<ggrid, 256, 0, stream>>>(ftab, norms, ltab /*S scratch*/, minmax, C, D);
    k_rowmax<<<C, 256, 0, stream>>>(ltab /*S*/, minmax, simval, simcls, C);

    // now overwrite the S scratch with the real logit_table
    k_ltab<<<C, 256, 0, stream>>>(logits, linit, counts, offsets, idx, ltab, C, C);

    k_floss<<<B / 4, 256, 0, stream>>>(feature, ftab, norms, targets, simval, simcls, fpart, B, D);
    k_kl<<<B / 4, 256, 0, stream>>>(logits, ltab, targets, klpart, B, C);
    k_final<<<1, 256, 0, stream>>>(fpart, klpart, out, B / 4, B);
}

// Round 5
// 180.623 us; speedup vs baseline: 2.1815x; 1.1153x over previous
//
#include <hip/hip_runtime.h>
#include <hip/hip_bf16.h>
#include <math.h>

#define EPS 1e-8f

// ---------- helpers ----------
__device__ __forceinline__ unsigned fenc(float f) {
    unsigned u = __float_as_uint(f);
    return (u & 0x80000000u) ? ~u : (u | 0x80000000u);
}
__device__ __forceinline__ float fdec(unsigned e) {
    unsigned u = (e & 0x80000000u) ? (e & 0x7FFFFFFFu) : ~e;
    return __uint_as_float(u);
}

__device__ __forceinline__ float block_sum(float v, float* red) {
    red[threadIdx.x] = v;
    __syncthreads();
    for (int k = 128; k > 0; k >>= 1) {
        if (threadIdx.x < k) red[threadIdx.x] += red[threadIdx.x + k];
        __syncthreads();
    }
    float r = red[0];
    __syncthreads();
    return r;
}

// ---------- kernels ----------
// per-group histogram: gh[g*1024 + c]
__global__ void k_ghist(const int* tgt, int* gh, int B) {
    __shared__ int lh[1024];
    int g = blockIdx.x, t = threadIdx.x;
    lh[t] = 0; lh[t + 256] = 0; lh[t + 512] = 0; lh[t + 768] = 0;
    __syncthreads();
    int i = g * 256 + t;
    if (i < B) atomicAdd(&lh[tgt[i]], 1);
    __syncthreads();
    int* dst = gh + g * 1024;
    dst[t] = lh[t]; dst[t + 256] = lh[t + 256];
    dst[t + 512] = lh[t + 512]; dst[t + 768] = lh[t + 768];
}

// in-place exclusive scan of gh over groups (per class), totals -> counts,
// class-exclusive-scan -> offsets. One block, 1024 threads. Also inits minmax.
__global__ void k_bases(int* gh, int* counts, int* offsets, unsigned* minmax, int G, int C) {
    __shared__ int buf[1024];
    int c = threadIdx.x;
    if (c == 0) { minmax[0] = 0xFFFFFFFFu; minmax[1] = 0u; }
    int run = 0;
    for (int g = 0; g < G; g++) {
        int v = gh[g * 1024 + c];
        gh[g * 1024 + c] = run;
        run += v;
    }
    if (c < C) counts[c] = run;
    int v0 = (c < C) ? run : 0;
    buf[c] = v0;
    __syncthreads();
    for (int off = 1; off < 1024; off <<= 1) {
        int v = (c >= off) ? buf[c - off] : 0;
        __syncthreads();
        buf[c] += v;
        __syncthreads();
    }
    if (c < C) offsets[c] = buf[c] - v0;
}

// stable rank within group via LDS compare-count; deterministic idx
__global__ void k_rank_scatter(const int* tgt, const int* offsets, const int* gh,
                               int* idx, int B) {
    __shared__ int lt[256];
    int g = blockIdx.x, t = threadIdx.x;
    int i = g * 256 + t;
    int my = (i < B) ? tgt[i] : -1;
    lt[t] = my;
    __syncthreads();
    if (i < B) {
        int rank = 0;
        for (int j = 0; j < t; j++) rank += (lt[j] == my);
        idx[offsets[my] + gh[g * 1024 + my] + rank] = i;
    }
}

// one block (256 thr) per class; D = 1024 (256 float4). Also emits norms.
__global__ void k_ftab(const float* feat, const float* finit, const int* counts,
                       const int* offsets, const int* idx, float* ftab, float* norms,
                       int C, int D) {
    __shared__ float red[256];
    int c = blockIdx.x, t = threadIdx.x;
    int n = counts[c];
    float o0, o1, o2, o3;
    if (n == 0) {
        float4 v = ((const float4*)(finit + (long)c * D))[t];
        o0 = v.x; o1 = v.y; o2 = v.z; o3 = v.w;
    } else {
        float4 acc = {0.f, 0.f, 0.f, 0.f};
        int o = offsets[c];
        for (int i = 0; i < n; i++) {
            float4 v = ((const float4*)(feat + (long)idx[o + i] * D))[t];
            acc.x += v.x; acc.y += v.y; acc.z += v.z; acc.w += v.w;
        }
        float inv = 1.0f / (float)n;
        o0 = acc.x * inv; o1 = acc.y * inv; o2 = acc.z * inv; o3 = acc.w * inv;
    }
    float* dst = ftab + (long)c * D + t * 4;   // ftab only 8B-aligned -> scalar writes
    dst[0] = o0; dst[1] = o1; dst[2] = o2; dst[3] = o3;
    float ss = o0 * o0 + o1 * o1 + o2 * o2 + o3 * o3;
    ss = block_sum(ss, red);
    if (t == 0) norms[c] = sqrtf(ss);
}

// one block per class; C2 = 1000 columns (250 float4 per row; logits rows 16B-aligned)
__global__ void k_ltab(const float* logits, const float* linit, const int* counts,
                       const int* offsets, const int* idx, float* ltab, int C, int C2) {
    int c = blockIdx.x, t = threadIdx.x;
    int n = counts[c];
    if (n == 0) {
        for (int d = t; d < C2; d += 256) ltab[(long)c * C2 + d] = linit[(long)c * C2 + d];
        return;
    }
    int nv = C2 >> 2;                 // 250
    if (t < nv) {
        float4 acc = {0.f, 0.f, 0.f, 0.f};
        int o = offsets[c];
        for (int i = 0; i < n; i++) {
            float4 v = ((const float4*)(logits + (long)idx[o + i] * C2))[t];
            acc.x += v.x; acc.y += v.y; acc.z += v.z; acc.w += v.w;
        }
        float inv = 1.0f / (float)n;
        float* dst = ltab + (long)c * C2 + t * 4;  // 8B-aligned -> scalar writes
        dst[0] = acc.x * inv;
        dst[1] = acc.y * inv;
        dst[2] = acc.z * inv;
        dst[3] = acc.w * inv;
    }
}

// S = (A A^T) / outer(norms)
// 64x64 tile / block, 512 thr (8 waves): kz=t/256 covers half of each 32-K tile.
// 4x4 per thread, K-major LDS, reg-prefetch of next tile, LDS reduction of kz halves.
__global__ __launch_bounds__(512) void k_gemm(const float* A, const float* norms, float* S,
                                              unsigned* minmax, int C, int D) {
    __shared__ __align__(16) float As[32][68];
    __shared__ __align__(16) float Bs[32][68];
    __shared__ float racc[256 * 17];      // kz=1 partial accs
    __shared__ float rmin[512], rmax[512];
    int t = threadIdx.x;
    int tx = t & 15, ty = (t >> 4) & 15, kz = t >> 8;
    int rb = blockIdx.y * 64, cb = blockIdx.x * 64;
    int sr = t >> 3;        // 0..63 staging row
    int sl = t & 7;         // 0..7  staging k-lane
    int ga = rb + sr, gb = cb + sr;
    bool okA = ga < C, okB = gb < C;
    const float* arow = A + (long)ga * D;
    const float* brow = A + (long)gb * D;

    float pa[4], pb[4];
#define LOADT(K0)                                                          \
    _Pragma("unroll") for (int j = 0; j < 4; j++) {                        \
        int k = (K0) + sl + 8 * j;                                         \
        pa[j] = okA ? arow[k] : 0.f;                                       \
        pb[j] = okB ? brow[k] : 0.f;                                       \
    }

    LOADT(0)
    float acc[4][4] = {};
    int kbase = kz * 16;
    for (int step = 0; step < 32; step++) {
        __syncthreads();
#pragma unroll
        for (int j = 0; j < 4; j++) {
            int k = sl + 8 * j;
            As[k][sr] = pa[j];
            Bs[k][sr] = pb[j];
        }
        __syncthreads();
        if (step < 31) {
            int k0n = (step + 1) * 32;
            LOADT(k0n)
        }
#pragma unroll
        for (int kk = 0; kk < 16; kk += 4) {
            float4 af[4], bf[4];
#pragma unroll
            for (int u = 0; u < 4; u++) {
                af[u] = *reinterpret_cast<const float4*>(&As[kbase + kk + u][ty * 4]);
                bf[u] = *reinterpret_cast<const float4*>(&Bs[kbase + kk + u][tx * 4]);
            }
#pragma unroll
            for (int u = 0; u < 4; u++) {
                float a[4] = {af[u].x, af[u].y, af[u].z, af[u].w};
                float b[4] = {bf[u].x, bf[u].y, bf[u].z, bf[u].w};
#pragma unroll
                for (int i = 0; i < 4; i++)
#pragma unroll
                    for (int j = 0; j < 4; j++) acc[i][j] += a[i] * b[j];
            }
        }
    }
#undef LOADT

    // reduce kz=1 partials into kz=0 (fixed order: acc0 + acc1)
    __syncthreads();
    if (kz == 1) {
#pragma unroll
        for (int i = 0; i < 4; i++)
#pragma unroll
            for (int j = 0; j < 4; j++) racc[(t - 256) * 17 + i * 4 + j] = acc[i][j];
    }
    __syncthreads();

    float lmin = INFINITY, lmax = -INFINITY;
    if (kz == 0) {
#pragma unroll
        for (int i = 0; i < 4; i++)
#pragma unroll
            for (int j = 0; j < 4; j++) acc[i][j] += racc[t * 17 + i * 4 + j];
        float nr[4], nc[4];
#pragma unroll
        for (int i = 0; i < 4; i++) {
            int r = rb + ty * 4 + i;
            nr[i] = (r < C) ? norms[r] : 1.f;
            int cc = cb + tx * 4 + i;
            nc[i] = (cc < C) ? norms[cc] : 1.f;
        }
#pragma unroll
        for (int i = 0; i < 4; i++) {
            int r = rb + ty * 4 + i;
            if (r >= C) continue;
#pragma unroll
            for (int j = 0; j < 4; j++) {
                int cc = cb + tx * 4 + j;
                if (cc >= C) continue;
                float v = acc[i][j] / (nr[i] * nc[j]);
                S[(long)r * C + cc] = v;
                lmin = fminf(lmin, v);
                lmax = fmaxf(lmax, v);
            }
        }
    }
    rmin[t] = lmin;
    rmax[t] = lmax;
    __syncthreads();
    for (int k = 256; k > 0; k >>= 1) {
        if (t < k) {
            rmin[t] = fminf(rmin[t], rmin[t + k]);
            rmax[t] = fmaxf(rmax[t], rmax[t + k]);
        }
        __syncthreads();
    }
    if (t == 0) {
        atomicMin(&minmax[0], fenc(rmin[0]));
        atomicMax(&minmax[1], fenc(rmax[0]));
    }
}

// per-row max/argmax excluding diagonal; normalize with cmin/cmax
__global__ void k_rowmax(const float* S, const unsigned* minmax, float* simval, int* simcls, int C) {
    __shared__ float rv[256];
    __shared__ int ri[256];
    int c = blockIdx.x, t = threadIdx.x;
    float best = -INFINITY;
    int bi = 0x7FFFFFFF;
    for (int j = t; j < C; j += 256) {
        if (j == c) continue;
        float v = S[(long)c * C + j];
        if (v > best) { best = v; bi = j; }
    }
    rv[t] = best;
    ri[t] = bi;
    __syncthreads();
    for (int k = 128; k > 0; k >>= 1) {
        if (t < k) {
            if (rv[t + k] > rv[t] || (rv[t + k] == rv[t] && ri[t + k] < ri[t])) {
                rv[t] = rv[t + k];
                ri[t] = ri[t + k];
            }
        }
        __syncthreads();
    }
    if (t == 0) {
        float cmin = fdec(minmax[0]);
        float cmax = fdec(minmax[1]);
        simval[c] = (rv[0] - cmin) / (cmax - cmin);
        simcls[c] = ri[0];
    }
}

// one wave per sample; 4 samples per block; vectorized loads
__global__ void k_floss(const float* feat, const float* ftab, const float* norms, const int* tgt,
                        const float* simval, const int* simcls, float* fpart, int B, int D) {
    int wid = threadIdx.x >> 6, lane = threadIdx.x & 63;
    int s = blockIdx.x * 4 + wid;
    int cls = tgt[s];
    int sc = simcls[cls];
    const float4* f4 = (const float4*)(feat + (long)s * D);           // 16B-aligned
    const float2* ft2 = (const float2*)(ftab + (long)cls * D);        // 8B-aligned
    const float2* fs2 = (const float2*)(ftab + (long)sc * D);
    float d1 = 0.f, d2 = 0.f, nf2 = 0.f;
#pragma unroll
    for (int i = 0; i < 4; i++) {
        int j = lane + i * 64;           // float4 index, 0..255
        float4 x = f4[j];
        float2 a0 = ft2[2 * j], a1 = ft2[2 * j + 1];
        float2 b0 = fs2[2 * j], b1 = fs2[2 * j + 1];
        d1 += x.x * a0.x + x.y * a0.y + x.z * a1.x + x.w * a1.y;
        d2 += x.x * b0.x + x.y * b0.y + x.z * b1.x + x.w * b1.y;
        nf2 += x.x * x.x + x.y * x.y + x.z * x.z + x.w * x.w;
    }
    for (int o = 32; o > 0; o >>= 1) {
        d1 += __shfl_down(d1, o);
        d2 += __shfl_down(d2, o);
        nf2 += __shfl_down(nf2, o);
    }
    __shared__ float part[4];
    if (lane == 0) {
        float nf = fmaxf(sqrtf(nf2), EPS);
        float nt = fmaxf(norms[cls], EPS);
        float ns = fmaxf(norms[sc], EPS);
        part[wid] = (1.f - d1 / (nf * nt)) + (d2 / (nf * ns)) * simval[cls];
    }
    __syncthreads();
    if (threadIdx.x == 0) fpart[blockIdx.x] = part[0] + part[1] + part[2] + part[3];
}

// one WAVE per sample; 4 samples per block; float2 loads, shuffle reductions. C even.
__global__ __launch_bounds__(256) void k_kl(const float* logits, const float* LT, const int* tgt,
                                            float* klpart, int B, int C) {
    int wid = threadIdx.x >> 6, lane = threadIdx.x & 63;
    int s = blockIdx.x * 4 + wid;
    int cls = tgt[s];
    const float2* a2 = (const float2*)(LT + (long)cls * C);      // 8B-aligned
    const float2* b2 = (const float2*)(logits + (long)s * C);    // 16B-aligned
    int H = C >> 1;   // 500
    float ta[16], tb[16];
    float m1 = -INFINITY, m2 = -INFINITY;
#pragma unroll
    for (int p = 0; p < 8; p++) {
        int j = lane + (p << 6);
        if (j < H) {
            float2 va = a2[j], vb = b2[j];
            ta[2 * p] = va.x; ta[2 * p + 1] = va.y;
            tb[2 * p] = vb.x; tb[2 * p + 1] = vb.y;
            m1 = fmaxf(m1, fmaxf(va.x, va.y));
            m2 = fmaxf(m2, fmaxf(vb.x, vb.y));
        } else {
            ta[2 * p] = -INFINITY; ta[2 * p + 1] = -INFINITY;
            tb[2 * p] = -INFINITY; tb[2 * p + 1] = -INFINITY;
        }
    }
#pragma unroll
    for (int o = 32; o > 0; o >>= 1) {
        m1 = fmaxf(m1, __shfl_xor(m1, o));
        m2 = fmaxf(m2, __shfl_xor(m2, o));
    }
    float e1[16];
    float s1 = 0.f, s2 = 0.f;
#pragma unroll
    for (int i = 0; i < 16; i++) {
        int j = lane + ((i >> 1) << 6);
        if (j < H) {
            e1[i] = expf(ta[i] - m1);
            s1 += e1[i];
            s2 += expf(tb[i] - m2);
        } else {
            e1[i] = 0.f;
        }
    }
#pragma unroll
    for (int o = 32; o > 0; o >>= 1) {
        s1 += __shfl_xor(s1, o);
        s2 += __shfl_xor(s2, o);
    }
    float ls1 = logf(s1), ls2 = logf(s2);
    float inv = 1.f / s1;
    float kl = 0.f;
#pragma unroll
    for (int i = 0; i < 16; i++) {
        int j = lane + ((i >> 1) << 6);
        if (j < H) {
            float lp = ta[i] - m1 - ls1;
            float lq = tb[i] - m2 - ls2;
            kl += e1[i] * inv * (lp - lq);
        }
    }
#pragma unroll
    for (int o = 32; o > 0; o >>= 1) kl += __shfl_xor(kl, o);
    if (lane == 0) klpart[s] = kl;
}

__global__ void k_final(const float* fpart, const float* klpart, float* out, int nf, int nk) {
    __shared__ float red[256];
    float a = 0.f;
    for (int i = threadIdx.x; i < nf; i += 256) a += fpart[i];
    a = block_sum(a, red);
    float b = 0.f;
    for (int i = threadIdx.x; i < nk; i += 256) b += klpart[i];
    b = block_sum(b, red);
    if (threadIdx.x == 0) {
        out[0] = a;
        out[1] = b;
    }
}

extern "C" void kernel_launch(void* const* d_in, const int* in_sizes, int n_in,
                              void* d_out, int out_size, void* d_ws, size_t ws_size,
                              hipStream_t stream) {
    const float* feature = (const float*)d_in[0];
    const float* logits  = (const float*)d_in[1];
    const int*   targets = (const int*)d_in[2];
    const float* finit   = (const float*)d_in[3];
    const float* linit   = (const float*)d_in[4];

    const int B = in_sizes[2];                 // 16384
    const int D = in_sizes[0] / B;             // 1024
    const int C = in_sizes[3] / D;             // 1000

    float* out = (float*)d_out;
    float* ftab = out + 2;                     // [C, D]
    float* ltab = out + 2 + (long)C * D;       // [C, C]  (S scratch + ghist scratch)

    const int G = (B + 255) / 256;             // 64 groups

    char* ws = (char*)d_ws;
    int*      counts  = (int*)(ws + 0);        // 1024
    int*      offsets = (int*)(ws + 4096);     // 1024
    int*      idx     = (int*)(ws + 12288);    // 16384
    float*    norms   = (float*)(ws + 77824);  // 1024
    float*    simval  = (float*)(ws + 81920);  // 1024
    int*      simcls  = (int*)(ws + 86016);    // 1024
    unsigned* minmax  = (unsigned*)(ws + 90112); // 2
    float*    fpart   = (float*)(ws + 90368);  // 4096
    float*    klpart  = (float*)(ws + 106752); // 16384

    // gh scratch lives in the (not-yet-written) ltab output region: G*1024 ints = 256 KB
    int* gh = (int*)ltab;

    k_ghist<<<G, 256, 0, stream>>>(targets, gh, B);
    k_bases<<<1, 1024, 0, stream>>>(gh, counts, offsets, minmax, G, C);
    k_rank_scatter<<<G, 256, 0, stream>>>(targets, offsets, gh, idx, B);

    k_ftab<<<C, 256, 0, stream>>>(feature, finit, counts, offsets, idx, ftab, norms, C, D);

    dim3 ggrid((C + 63) / 64, (C + 63) / 64);
    k_gemm<<<ggrid, 512, 0, stream>>>(ftab, norms, ltab /*S scratch*/, minmax, C, D);
    k_rowmax<<<C, 256, 0, stream>>>(ltab /*S*/, minmax, simval, simcls, C);

    // now overwrite the S scratch with the real logit_table
    k_ltab<<<C, 256, 0, stream>>>(logits, linit, counts, offsets, idx, ltab, C, C);

    k_floss<<<B / 4, 256, 0, stream>>>(feature, ftab, norms, targets, simval, simcls, fpart, B, D);
    k_kl<<<B / 4, 256, 0, stream>>>(logits, ltab, targets, klpart, B, C);
    k_final<<<1, 256, 0, stream>>>(fpart, klpart, out, B / 4, B);
}